// Round 13
// baseline (125.570 us; speedup 1.0000x reference)
//
#include <hip/hip_runtime.h>
#include <hip/hip_fp16.h>

// KANLayer: out = (relu(x[:,:,None]*W1+b1) . W2 + b2) @ Wc^T + bc
// B=16384, D=256, H=64, O=256.
// v9: weights delivered via LDS uniform-broadcast (no SGPR-budget stall, no
//     bank conflicts), DMA-staged per wave (wave-private -> ZERO barriers).
//     4 rows/thread amortize each weight read over 4x VALU. Packed f16 core.
//     p2 = zero-LDS streaming MFMA GEMM on fragment-ordered u (unchanged v8).
#define B_N 16384
#define D_N 256
#define H_N 64
#define O_N 256

typedef unsigned int u32;
typedef unsigned short u16;
typedef _Float16 f16;
typedef __attribute__((ext_vector_type(2))) _Float16 f16x2;
typedef __attribute__((ext_vector_type(8))) _Float16 f16x8;
typedef __attribute__((ext_vector_type(4))) float f32x4;
typedef __attribute__((ext_vector_type(4))) u32 uint4v;
typedef __attribute__((ext_vector_type(4))) u16 u16x4;

// Packed params, rewritten by prep() every launch (idempotent -> graph-safe).
// g_Wf layout: [d][arr][j] u32, arr in {w1,b1,w2}, j = h-pair 0..31. 96KB.
__device__ __attribute__((aligned(16))) u32 g_Wf[D_N * 96];
__device__ __attribute__((aligned(16))) u16 g_Wch[O_N * D_N];  // f16(Wc)
// u in MFMA-A-fragment order: [b>>4][kb=d>>3][b&15][d&7], 8MB (BSS)
__device__ __attribute__((aligned(16))) u16 g_Uf[B_N * D_N];

union HU { f16 h; u16 b; };

static __device__ __forceinline__ u32 packh2(float a, float b) {
  f16x2 p = {(f16)a, (f16)b};
  return __builtin_bit_cast(u32, p);
}
static __device__ __forceinline__ u16 f16b(float a) { HU u; u.h = (f16)a; return u.b; }
static __device__ __forceinline__ f16x2 ash2(u32 w) { return __builtin_bit_cast(f16x2, w); }

#if __has_builtin(__builtin_amdgcn_fdot2)
#define FDOT2(a, b, c) __builtin_amdgcn_fdot2((a), (b), (c), false)
#else
#define FDOT2(a, b, c) \
  fmaf((float)(a)[0], (float)(b)[0], fmaf((float)(a)[1], (float)(b)[1], (c)))
#endif

static __device__ __forceinline__ void dma16(const u32* g, u32* l) {
  __builtin_amdgcn_global_load_lds(
      (const __attribute__((address_space(1))) u32*)g,
      (__attribute__((address_space(3))) u32*)l, 16, 0, 0);
}

__global__ __launch_bounds__(256) void prep(
    const float* __restrict__ W1, const float* __restrict__ b1,
    const float* __restrict__ W2, const float* __restrict__ Wc) {
  const int t = blockIdx.x * 256 + threadIdx.x;  // 0..16383
  if ((t & 1) == 0) {
    const int d = t >> 6, j = (t & 63) >> 1;
    g_Wf[d * 96 + j]      = packh2(W1[t], W1[t + 1]);
    g_Wf[d * 96 + 32 + j] = packh2(b1[t], b1[t + 1]);
    g_Wf[d * 96 + 64 + j] = packh2(W2[t], W2[t + 1]);
  }
  const int i4 = t * 4;  // 65536 Wc elements, 4/thread
  const f32x4 v = *reinterpret_cast<const f32x4*>(Wc + i4);
  u16x4 s;
#pragma unroll
  for (int q = 0; q < 4; ++q) s[q] = f16b(v[q]);
  *reinterpret_cast<u16x4*>(g_Wch + i4) = s;
}

// ---- phase 1: block = 256 rows x 32 d; wave wv owns 8 d, lane owns 4 rows ----
__global__ __launch_bounds__(256, 2) void kan_p1(const float* __restrict__ x,
                                                 const float* __restrict__ b2) {
  __shared__ u32 wlds[4 * 768];  // 12KB; per-wave private 3KB

  const int tid  = threadIdx.x;
  const int lane = tid & 63;
  const int wv   = tid >> 6;
  const int bs   = blockIdx.x >> 3;           // row stripe (256 rows)
  const int dg   = blockIdx.x & 7;            // d-group (32 d)
  const int d0   = dg * 32 + wv * 8;          // wave-uniform 8 d
  const int rb   = bs * 256 + lane;           // lane's base row

  // DMA the wave's 3KB weight slab (linear) -- wave-private, no barrier ever.
  {
    const u32* src = g_Wf + d0 * 96;
    u32* dst = wlds + wv * 768;
#pragma unroll
    for (int i = 0; i < 3; ++i) dma16(src + i * 256 + lane * 4, dst + i * 256);
  }

  // x[rb + 64r][d0..d0+7] -> f16 broadcast pairs (overlaps DMA flight)
  f16x2 xx[4][8];
#pragma unroll
  for (int r = 0; r < 4; ++r) {
    const float* xp = x + (size_t)(rb + r * 64) * D_N + d0;
    const f32x4 a = *reinterpret_cast<const f32x4*>(xp);
    const f32x4 b = *reinterpret_cast<const f32x4*>(xp + 4);
#pragma unroll
    for (int e = 0; e < 4; ++e) {
      const f16 ha = (f16)a[e], hb = (f16)b[e];
      xx[r][e]     = (f16x2){ha, ha};
      xx[r][4 + e] = (f16x2){hb, hb};
    }
  }

  asm volatile("s_waitcnt vmcnt(0)" ::: "memory");  // DMA landed

  const u32* wl = wlds + wv * 768;
  uint4v pkv[4];  // per-row packed 8xf16 output fragment
#pragma unroll
  for (int dd = 0; dd < 8; ++dd) {
    const float b2v = b2[d0 + dd];  // uniform (s_load)
    float acc[4] = {0.f, 0.f, 0.f, 0.f};
#pragma unroll
    for (int jq = 0; jq < 8; ++jq) {
      // uniform-address b128 reads: broadcast, conflict-free
      const uint4v w1q = *reinterpret_cast<const uint4v*>(wl + dd * 96 + jq * 4);
      const uint4v b1q = *reinterpret_cast<const uint4v*>(wl + dd * 96 + 32 + jq * 4);
      const uint4v w2q = *reinterpret_cast<const uint4v*>(wl + dd * 96 + 64 + jq * 4);
#pragma unroll
      for (int k = 0; k < 4; ++k) {
        const f16x2 w1 = ash2(w1q[k]), bb = ash2(b1q[k]), w2 = ash2(w2q[k]);
#pragma unroll
        for (int r = 0; r < 4; ++r) {
          f16x2 tv = __builtin_elementwise_fma(xx[r][dd], w1, bb);  // v_pk_fma_f16
          tv = __builtin_elementwise_max(tv, (f16x2){(f16)0.f, (f16)0.f});
          acc[r] = FDOT2(tv, w2, acc[r]);  // v_dot2_f32_f16, f32 accum
        }
      }
    }
#pragma unroll
    for (int r = 0; r < 4; ++r) {
      const u16 hv = f16b(acc[r] + b2v);
      if ((dd & 1) == 0) pkv[r][dd >> 1] = (u32)hv;
      else               pkv[r][dd >> 1] |= ((u32)hv) << 16;
    }
  }

  // fragment-ordered coalesced writes (16-lane groups -> 256B contiguous)
#pragma unroll
  for (int r = 0; r < 4; ++r) {
    const int row = rb + r * 64;
    u16* p = g_Uf + (size_t)((row >> 4) * 32 + (d0 >> 3)) * 128 + (row & 15) * 8;
    *reinterpret_cast<uint4v*>(p) = pkv[r];
  }
}

// ---- phase 2: out = u @ Wc^T + bc. Zero LDS, zero barriers. ----
__global__ __launch_bounds__(256) void kan_p2(const float* __restrict__ bc,
                                              float* __restrict__ out) {
  const int t    = threadIdx.x;
  const int wv   = t >> 6, dl = t & 63;
  const int mt   = blockIdx.x;        // 16-row M tile
  const int n0   = wv * 64;
  const int mrow = dl & 15;
  const int kgrp = dl >> 4;
  const int b0   = mt * 16;

  f32x4 acc2[4];
#pragma unroll
  for (int j = 0; j < 4; ++j) acc2[j] = (f32x4)(0.f);

#pragma unroll
  for (int ks = 0; ks < 8; ++ks) {
    const int k0 = ks * 32 + kgrp * 8;
    const f16x8 afrag = *reinterpret_cast<const f16x8*>(
        g_Uf + (mt * 32 + ks * 4 + kgrp) * 128 + mrow * 8);  // coalesced 16B
#pragma unroll
    for (int j = 0; j < 4; ++j) {
      const f16x8 bfrag = *reinterpret_cast<const f16x8*>(
          g_Wch + (n0 + j * 16 + mrow) * D_N + k0);          // L2-resident
      acc2[j] = __builtin_amdgcn_mfma_f32_16x16x32_f16(afrag, bfrag, acc2[j],
                                                       0, 0, 0);
    }
  }

  // epilogue: C/D map col=lane&15, row=4*(lane>>4)+q (m89-verified)
#pragma unroll
  for (int j = 0; j < 4; ++j) {
    const int colg = n0 + j * 16 + mrow;
    const float bcv = bc[colg];
#pragma unroll
    for (int q = 0; q < 4; ++q) {
      const int rowg = b0 + kgrp * 4 + q;
      out[rowg * O_N + colg] = acc2[j][q] + bcv;
    }
  }
}

extern "C" void kernel_launch(void* const* d_in, const int* in_sizes, int n_in,
                              void* d_out, int out_size, void* d_ws, size_t ws_size,
                              hipStream_t stream) {
  const float* x  = (const float*)d_in[0];
  const float* W1 = (const float*)d_in[1];
  const float* b1 = (const float*)d_in[2];
  const float* W2 = (const float*)d_in[3];
  const float* b2 = (const float*)d_in[4];
  const float* Wc = (const float*)d_in[5];
  const float* bc = (const float*)d_in[6];
  float* out = (float*)d_out;

  prep<<<dim3(D_N * H_N / 256), dim3(256), 0, stream>>>(W1, b1, W2, Wc);
  kan_p1<<<dim3((B_N / 256) * (D_N / 32)), dim3(256), 0, stream>>>(x, b2);
  kan_p2<<<dim3(B_N / 16), dim3(256), 0, stream>>>(bc, out);
}